// Round 10
// baseline (43684.943 us; speedup 1.0000x reference)
//
#include <hip/hip_runtime.h>
#include <hip/hip_bf16.h>

#define B_   64
#define T_   2048
#define F_   256
#define H_   512
#define GB   4                    // batch groups (16 rows each)
#define GG   8                    // gate-split WGs per group
#define NWG  (GB*GG)              // 32
#define PAYD 4096                 // payload dwords per group: 16 rows * 256 pairs

typedef __attribute__((ext_vector_type(8))) short bfrag;   // 8 bf16 (MFMA A/B)
typedef __attribute__((ext_vector_type(4))) int   int4v;
typedef __attribute__((ext_vector_type(4))) float f32x4;
typedef __attribute__((ext_vector_type(4))) float float4_t;

__device__ __forceinline__ float fsig(float x)  { return 1.0f / (1.0f + __expf(-x)); }
__device__ __forceinline__ float ftanh(float x) { return 2.0f / (1.0f + __expf(-2.0f * x)) - 1.0f; }
__device__ __forceinline__ short f2bf(float f) {
  __hip_bfloat16 h = __float2bfloat16(f);
  return __builtin_bit_cast(short, h);
}

// ---- coherence-point (sc0 sc1: bypass L1+L2, serviced at MALL) ----
__device__ __forceinline__ int gload4_cc(const void* p) {
  int r;
  asm volatile("global_load_dword %0, %1, off sc0 sc1" : "=v"(r) : "v"(p));
  return r;
}
__device__ __forceinline__ void gstore4_cc(void* p, int d) {
  asm volatile("global_store_dword %0, %1, off sc0 sc1" :: "v"(p), "v"(d));
}
__device__ __forceinline__ int gload_flag(const void* p) {
  int r;
  asm volatile("global_load_dword %0, %1, off sc0 sc1\n\ts_waitcnt vmcnt(0)"
               : "=v"(r) : "v"(p) : "memory");
  return r;
}
__device__ __forceinline__ void vm_drain() {
  asm volatile("s_waitcnt vmcnt(0)" ::: "memory");
  __builtin_amdgcn_sched_barrier(0);   // rule #18
}

// ---------------- init: h0 payload into buf0, all flags = 0 ----------------
__global__ void lstm_init(const float* __restrict__ z, int* __restrict__ pay,
                          int* __restrict__ flags, int* __restrict__ flags2) {
  int i = blockIdx.x * blockDim.x + threadIdx.x;     // 0..16383
  if (i < GB * 16) { flags[i] = 0; flags2[i] = 0; }
  int g  = i >> 12;            // group
  int p  = i & 4095;           // payload dword within group
  int j  = p >> 8;             // row within group
  int pr = p & 255;            // col pair
  int row = 16 * g + j;
  int lo = (int)((unsigned)(unsigned short)f2bf(z[(size_t)row * H_ + 2 * pr])
         | ((unsigned)(unsigned short)f2bf(z[(size_t)row * H_ + 2 * pr + 1]) << 16));
  pay[(size_t)g * PAYD + p] = lo;                    // parity-0 buffer
}

// ========================= ABLATION VARIANTS (ws-only) ========================

// V1: full compute + identical UC byte traffic, ZERO waiting (no flags/poll).
// WG reads/writes a (shared-by-4-WGs) 16KB slot; values are junk but live.
__global__ void __launch_bounds__(256, 1)
v_nocomm(const float* __restrict__ x,
         const float* __restrict__ Wih,  const float* __restrict__ Whh,
         const float* __restrict__ bih,  const float* __restrict__ bhh,
         const float* __restrict__ Wlin, const float* __restrict__ blin,
         float* __restrict__ dump, int* __restrict__ pay2)
{
  __shared__ char smem[49152];
  const int wg  = blockIdx.x;
  const int b   = wg >> 3;
  const int k   = wg & 7;
  const int tid = threadIdx.x;
  const int wv  = tid >> 6;
  const int l   = tid & 63;
  const int l16 = l & 15;
  const int qq  = l >> 4;
  const int swz = (l16 & 7) << 4;
  const int m4  = qq << 2;

  {
    const int oc = tid >> 3;
    const float* src = Wlin + (size_t)(32 * k + oc) * H_ + (tid & 7) * 64;
    char* dst = smem + 16384 + oc * 1024;
    #pragma unroll
    for (int i = 0; i < 8; ++i) {
      bfrag tmp;
      #pragma unroll
      for (int e = 0; e < 8; ++e) tmp[e] = f2bf(src[i * 8 + e]);
      *(int4v*)(dst + ((((tid & 7) * 128) + i * 16) ^ ((oc & 7) << 4))) =
          __builtin_bit_cast(int4v, tmp);
    }
  }
  bfrag WH[4][16]; bfrag WI[4][8]; float bs[4];
  #pragma unroll
  for (int q = 0; q < 4; ++q) {
    const int grow = q * H_ + k * 64 + wv * 16 + l16;
    #pragma unroll
    for (int kt = 0; kt < 16; ++kt) {
      const float* s = Whh + (size_t)grow * H_ + kt * 32 + qq * 8;
      bfrag w;
      #pragma unroll
      for (int e = 0; e < 8; ++e) w[e] = f2bf(s[e]);
      WH[q][kt] = w;
    }
    #pragma unroll
    for (int kt = 0; kt < 8; ++kt) {
      const float* s = Wih + (size_t)grow * F_ + kt * 32 + qq * 8;
      bfrag w;
      #pragma unroll
      for (int e = 0; e < 8; ++e) w[e] = f2bf(s[e]);
      WI[q][kt] = w;
    }
    bs[q] = bih[grow] + bhh[grow];
  }
  const float blc = (wv < 2) ? blin[32 * k + 16 * wv + l16] : 0.f;
  float c4[4] = {0.f, 0.f, 0.f, 0.f};
  __syncthreads();

  int* slot = pay2 + (size_t)(wg & 7) * PAYD;   // 8 slots, 4 WGs each (junk ok)

  for (int t = 0; t < T_; ++t) {
    // A: x-part (real)
    f32x4 acc[4] = {{0,0,0,0},{0,0,0,0},{0,0,0,0},{0,0,0,0}};
    {
      const float* xr = x + ((size_t)(16 * b + l16) * T_ + t) * F_ + qq * 8;
      #pragma unroll
      for (int kt = 0; kt < 8; ++kt) {
        float4_t xa = *(const float4_t*)(xr + kt * 32);
        float4_t xb = *(const float4_t*)(xr + kt * 32 + 4);
        bfrag a;
        #pragma unroll
        for (int e = 0; e < 4; ++e) { a[e] = f2bf(xa[e]); a[4 + e] = f2bf(xb[e]); }
        #pragma unroll
        for (int q = 0; q < 4; ++q)
          acc[q] = __builtin_amdgcn_mfma_f32_16x16x32_bf16(a, WI[q][kt], acc[q], 0, 0, 0);
      }
    }
    // B': payload read, NO poll
    int pv[16];
    #pragma unroll
    for (int j = 0; j < 16; ++j) pv[j] = gload4_cc(slot + tid + j * 256);
    vm_drain();
    __syncthreads();
    // C
    #pragma unroll
    for (int j = 0; j < 16; ++j)
      *(int*)(smem + j * 1024 + ((tid * 4) ^ ((j & 7) << 4))) = pv[j];
    __syncthreads();
    // D
    f32x4 oacc = {blc, blc, blc, blc};
    #pragma unroll
    for (int kt = 0; kt < 16; ++kt) {
      bfrag a = *(const bfrag*)(smem + l16 * 1024 + ((kt * 64 + qq * 16) ^ swz));
      #pragma unroll
      for (int q = 0; q < 4; ++q)
        acc[q] = __builtin_amdgcn_mfma_f32_16x16x32_bf16(a, WH[q][kt], acc[q], 0, 0, 0);
      if (wv < 2) {
        bfrag wl = *(const bfrag*)(smem + 16384 + (16 * wv + l16) * 1024 +
                                   ((kt * 64 + qq * 16) ^ swz));
        oacc = __builtin_amdgcn_mfma_f32_16x16x32_bf16(a, wl, oacc, 0, 0, 0);
      }
    }
    // E (stores to own slot; no flag)
    #pragma unroll
    for (int r = 0; r < 4; ++r) {
      float iv = fsig(acc[0][r] + bs[0]);
      float fv = fsig(acc[1][r] + bs[1]);
      float gv = ftanh(acc[2][r] + bs[2]);
      float ov = fsig(acc[3][r] + bs[3]);
      float cn = fv * c4[r] + iv * gv;
      c4[r] = cn;
      float hn = ov * ftanh(cn);
      int hb = (int)(unsigned short)f2bf(hn);
      int pu = __shfl_xor(hb, 1);
      if ((l16 & 1) == 0) {
        int packed = (hb & 0xffff) | (pu << 16);
        gstore4_cc(slot + (m4 + r) * 256 + (32 * k + 8 * wv + (l16 >> 1)), packed);
      }
    }
    vm_drain();
    __syncthreads();
    // F -> dump
    if (t > 0 && wv < 2) {
      #pragma unroll
      for (int r = 0; r < 4; ++r)
        dump[wg * 1024 + ((tid * 4 + r) & 1023)] = oacc[r];
    }
  }
}

// V2: full protocol (flags + payload read-once + stores + drain + flag), NO compute.
__global__ void __launch_bounds__(256, 1)
v_onlycomm(int* __restrict__ pay2, int* __restrict__ flags2)
{
  const int wg  = blockIdx.x;
  const int b   = wg >> 3;
  const int k   = wg & 7;
  const int tid = threadIdx.x;
  const int wv  = tid >> 6;
  const int l   = tid & 63;
  const int l16 = l & 15;
  const int qq  = l >> 4;
  const int m4  = qq << 2;
  const int* myflags = flags2 + b * 16;
  int guard = 0;

  for (int t = 0; t < T_; ++t) {
    if (t > 0) {
      while (true) {
        int v = gload_flag(&myflags[l & 7]);
        if (__all(v >= t)) break;
        if (++guard > 30000) return;
        __builtin_amdgcn_s_sleep(1);
      }
      __builtin_amdgcn_sched_barrier(0);
    }
    const int* pp = pay2 + (size_t)((t & 1) * GB + b) * PAYD + tid;
    int pv[16];
    #pragma unroll
    for (int j = 0; j < 16; ++j) pv[j] = gload4_cc(pp + j * 256);
    vm_drain();
    __syncthreads();

    int* ps = pay2 + (size_t)(((t + 1) & 1) * GB + b) * PAYD;
    #pragma unroll
    for (int r = 0; r < 4; ++r) {
      if ((l16 & 1) == 0)
        gstore4_cc(ps + (m4 + r) * 256 + (32 * k + 8 * wv + (l16 >> 1)), pv[r]);
    }
    vm_drain();
    __syncthreads();
    if (tid == 0)
      gstore4_cc((void*)&flags2[b * 16 + k], t + 1);
  }
}

// V3: production minus phase A (x-part). Flags continue at base 2048.
__global__ void __launch_bounds__(256, 1)
v_noA(const float* __restrict__ Whh, const float* __restrict__ bih,
      const float* __restrict__ bhh, const float* __restrict__ Wlin,
      const float* __restrict__ blin, float* __restrict__ dump,
      int* __restrict__ pay2, int* __restrict__ flags2)
{
  __shared__ char smem[49152];
  const int wg  = blockIdx.x;
  const int b   = wg >> 3;
  const int k   = wg & 7;
  const int tid = threadIdx.x;
  const int wv  = tid >> 6;
  const int l   = tid & 63;
  const int l16 = l & 15;
  const int qq  = l >> 4;
  const int swz = (l16 & 7) << 4;
  const int m4  = qq << 2;
  const int TB  = 2048;

  {
    const int oc = tid >> 3;
    const float* src = Wlin + (size_t)(32 * k + oc) * H_ + (tid & 7) * 64;
    char* dst = smem + 16384 + oc * 1024;
    #pragma unroll
    for (int i = 0; i < 8; ++i) {
      bfrag tmp;
      #pragma unroll
      for (int e = 0; e < 8; ++e) tmp[e] = f2bf(src[i * 8 + e]);
      *(int4v*)(dst + ((((tid & 7) * 128) + i * 16) ^ ((oc & 7) << 4))) =
          __builtin_bit_cast(int4v, tmp);
    }
  }
  bfrag WH[4][16]; float bs[4];
  #pragma unroll
  for (int q = 0; q < 4; ++q) {
    const int grow = q * H_ + k * 64 + wv * 16 + l16;
    #pragma unroll
    for (int kt = 0; kt < 16; ++kt) {
      const float* s = Whh + (size_t)grow * H_ + kt * 32 + qq * 8;
      bfrag w;
      #pragma unroll
      for (int e = 0; e < 8; ++e) w[e] = f2bf(s[e]);
      WH[q][kt] = w;
    }
    bs[q] = bih[grow] + bhh[grow];
  }
  const float blc = (wv < 2) ? blin[32 * k + 16 * wv + l16] : 0.f;
  float c4[4] = {0.f, 0.f, 0.f, 0.f};
  __syncthreads();
  const int* myflags = flags2 + b * 16;
  int guard = 0;

  for (int t = 0; t < T_; ++t) {
    f32x4 acc[4] = {{0,0,0,0},{0,0,0,0},{0,0,0,0},{0,0,0,0}};   // no x-part
    {
      while (true) {
        int v = gload_flag(&myflags[l & 7]);
        if (__all(v >= TB + t)) break;
        if (++guard > 30000) return;
        __builtin_amdgcn_s_sleep(1);
      }
      __builtin_amdgcn_sched_barrier(0);
    }
    const int* pp = pay2 + (size_t)((t & 1) * GB + b) * PAYD + tid;
    int pv[16];
    #pragma unroll
    for (int j = 0; j < 16; ++j) pv[j] = gload4_cc(pp + j * 256);
    vm_drain();
    __syncthreads();
    #pragma unroll
    for (int j = 0; j < 16; ++j)
      *(int*)(smem + j * 1024 + ((tid * 4) ^ ((j & 7) << 4))) = pv[j];
    __syncthreads();

    f32x4 oacc = {blc, blc, blc, blc};
    #pragma unroll
    for (int kt = 0; kt < 16; ++kt) {
      bfrag a = *(const bfrag*)(smem + l16 * 1024 + ((kt * 64 + qq * 16) ^ swz));
      #pragma unroll
      for (int q = 0; q < 4; ++q)
        acc[q] = __builtin_amdgcn_mfma_f32_16x16x32_bf16(a, WH[q][kt], acc[q], 0, 0, 0);
      if (wv < 2) {
        bfrag wl = *(const bfrag*)(smem + 16384 + (16 * wv + l16) * 1024 +
                                   ((kt * 64 + qq * 16) ^ swz));
        oacc = __builtin_amdgcn_mfma_f32_16x16x32_bf16(a, wl, oacc, 0, 0, 0);
      }
    }
    int* ps = pay2 + (size_t)(((t + 1) & 1) * GB + b) * PAYD;
    #pragma unroll
    for (int r = 0; r < 4; ++r) {
      float iv = fsig(acc[0][r] + bs[0]);
      float fv = fsig(acc[1][r] + bs[1]);
      float gv = ftanh(acc[2][r] + bs[2]);
      float ov = fsig(acc[3][r] + bs[3]);
      float cn = fv * c4[r] + iv * gv;
      c4[r] = cn;
      float hn = ov * ftanh(cn);
      int hb = (int)(unsigned short)f2bf(hn);
      int pu = __shfl_xor(hb, 1);
      if ((l16 & 1) == 0) {
        int packed = (hb & 0xffff) | (pu << 16);
        gstore4_cc(ps + (m4 + r) * 256 + (32 * k + 8 * wv + (l16 >> 1)), packed);
      }
    }
    vm_drain();
    __syncthreads();
    if (tid == 0)
      gstore4_cc((void*)&flags2[b * 16 + k], TB + t + 1);
    if (t > 0 && wv < 2) {
      #pragma unroll
      for (int r = 0; r < 4; ++r)
        dump[32 * 1024 + wg * 1024 + ((tid * 4 + r) & 1023)] = oacc[r];
    }
  }
}

// ---------------- persistent LSTM (R9 verbatim — production) ----------------
__global__ void __launch_bounds__(256, 1)
lstm_persist(const float* __restrict__ x,
             const float* __restrict__ Wih,  const float* __restrict__ Whh,
             const float* __restrict__ bih,  const float* __restrict__ bhh,
             const float* __restrict__ Wlin, const float* __restrict__ blin,
             float* __restrict__ out, int* __restrict__ pay,
             int* __restrict__ flags)
{
  __shared__ char smem[49152];

  const int wg  = blockIdx.x;
  const int b   = wg >> 3;
  const int k   = wg & 7;
  const int tid = threadIdx.x;
  const int wv  = tid >> 6;
  const int l   = tid & 63;
  const int l16 = l & 15;
  const int qq  = l >> 4;
  const int swz = (l16 & 7) << 4;
  const int m4  = qq << 2;

  {
    const int oc = tid >> 3;
    const float* src = Wlin + (size_t)(32 * k + oc) * H_ + (tid & 7) * 64;
    char* dst = smem + 16384 + oc * 1024;
    #pragma unroll
    for (int i = 0; i < 8; ++i) {
      bfrag tmp;
      #pragma unroll
      for (int e = 0; e < 8; ++e) tmp[e] = f2bf(src[i * 8 + e]);
      *(int4v*)(dst + ((((tid & 7) * 128) + i * 16) ^ ((oc & 7) << 4))) =
          __builtin_bit_cast(int4v, tmp);
    }
  }

  bfrag WH[4][16]; bfrag WI[4][8]; float bs[4];
  #pragma unroll
  for (int q = 0; q < 4; ++q) {
    const int grow = q * H_ + k * 64 + wv * 16 + l16;
    #pragma unroll
    for (int kt = 0; kt < 16; ++kt) {
      const float* s = Whh + (size_t)grow * H_ + kt * 32 + qq * 8;
      bfrag w;
      #pragma unroll
      for (int e = 0; e < 8; ++e) w[e] = f2bf(s[e]);
      WH[q][kt] = w;
    }
    #pragma unroll
    for (int kt = 0; kt < 8; ++kt) {
      const float* s = Wih + (size_t)grow * F_ + kt * 32 + qq * 8;
      bfrag w;
      #pragma unroll
      for (int e = 0; e < 8; ++e) w[e] = f2bf(s[e]);
      WI[q][kt] = w;
    }
    bs[q] = bih[grow] + bhh[grow];
  }
  const float blc = (wv < 2) ? blin[32 * k + 16 * wv + l16] : 0.f;

  float c4[4] = {0.f, 0.f, 0.f, 0.f};
  __syncthreads();

  const int* myflags = flags + b * 16;

  for (int t = 0; t < T_; ++t) {
    f32x4 acc[4] = {{0,0,0,0},{0,0,0,0},{0,0,0,0},{0,0,0,0}};
    {
      const float* xr = x + ((size_t)(16 * b + l16) * T_ + t) * F_ + qq * 8;
      #pragma unroll
      for (int kt = 0; kt < 8; ++kt) {
        float4_t xa = *(const float4_t*)(xr + kt * 32);
        float4_t xb = *(const float4_t*)(xr + kt * 32 + 4);
        bfrag a;
        #pragma unroll
        for (int e = 0; e < 4; ++e) { a[e] = f2bf(xa[e]); a[4 + e] = f2bf(xb[e]); }
        #pragma unroll
        for (int q = 0; q < 4; ++q)
          acc[q] = __builtin_amdgcn_mfma_f32_16x16x32_bf16(a, WI[q][kt], acc[q], 0, 0, 0);
      }
    }

    if (t > 0) {
      while (true) {
        int v = gload_flag(&myflags[l & 7]);
        if (__all(v >= t)) break;
        __builtin_amdgcn_s_sleep(1);
      }
      __builtin_amdgcn_sched_barrier(0);
    }
    const int* pp = pay + (size_t)((t & 1) * GB + b) * PAYD + tid;
    int pv[16];
    #pragma unroll
    for (int j = 0; j < 16; ++j) pv[j] = gload4_cc(pp + j * 256);
    vm_drain();
    __syncthreads();

    #pragma unroll
    for (int j = 0; j < 16; ++j)
      *(int*)(smem + j * 1024 + ((tid * 4) ^ ((j & 7) << 4))) = pv[j];
    __syncthreads();

    f32x4 oacc = {blc, blc, blc, blc};
    #pragma unroll
    for (int kt = 0; kt < 16; ++kt) {
      bfrag a = *(const bfrag*)(smem + l16 * 1024 + ((kt * 64 + qq * 16) ^ swz));
      #pragma unroll
      for (int q = 0; q < 4; ++q)
        acc[q] = __builtin_amdgcn_mfma_f32_16x16x32_bf16(a, WH[q][kt], acc[q], 0, 0, 0);
      if (wv < 2) {
        bfrag wl = *(const bfrag*)(smem + 16384 + (16 * wv + l16) * 1024 +
                                   ((kt * 64 + qq * 16) ^ swz));
        oacc = __builtin_amdgcn_mfma_f32_16x16x32_bf16(a, wl, oacc, 0, 0, 0);
      }
    }

    int* ps = pay + (size_t)(((t + 1) & 1) * GB + b) * PAYD;
    #pragma unroll
    for (int r = 0; r < 4; ++r) {
      float iv = fsig(acc[0][r] + bs[0]);
      float fv = fsig(acc[1][r] + bs[1]);
      float gv = ftanh(acc[2][r] + bs[2]);
      float ov = fsig(acc[3][r] + bs[3]);
      float cn = fv * c4[r] + iv * gv;
      c4[r] = cn;
      float hn = ov * ftanh(cn);
      int hb = (int)(unsigned short)f2bf(hn);
      int pu = __shfl_xor(hb, 1);
      if ((l16 & 1) == 0) {
        int packed = (hb & 0xffff) | (pu << 16);
        gstore4_cc(ps + (m4 + r) * 256 + (32 * k + 8 * wv + (l16 >> 1)), packed);
      }
    }
    vm_drain();
    __syncthreads();
    if (tid == 0)
      gstore4_cc((void*)&flags[b * 16 + k], t + 1);

    if (t > 0 && wv < 2) {
      #pragma unroll
      for (int r = 0; r < 4; ++r)
        out[(size_t)(16 * b + m4 + r) * T_ * F_ + (size_t)(t - 1) * F_ +
            32 * k + 16 * wv + l16] = oacc[r];
    }
  }

  {
    while (true) {
      int v = gload_flag(&myflags[l & 7]);
      if (__all(v >= T_)) break;
      __builtin_amdgcn_s_sleep(1);
    }
    __builtin_amdgcn_sched_barrier(0);

    const int* pp = pay + (size_t)((T_ & 1) * GB + b) * PAYD + tid;
    int pv[16];
    #pragma unroll
    for (int j = 0; j < 16; ++j) pv[j] = gload4_cc(pp + j * 256);
    vm_drain();
    __syncthreads();
    #pragma unroll
    for (int j = 0; j < 16; ++j)
      *(int*)(smem + j * 1024 + ((tid * 4) ^ ((j & 7) << 4))) = pv[j];
    __syncthreads();

    if (wv < 2) {
      f32x4 oacc = {blc, blc, blc, blc};
      #pragma unroll
      for (int kt = 0; kt < 16; ++kt) {
        bfrag a  = *(const bfrag*)(smem + l16 * 1024 + ((kt * 64 + qq * 16) ^ swz));
        bfrag wl = *(const bfrag*)(smem + 16384 + (16 * wv + l16) * 1024 +
                                   ((kt * 64 + qq * 16) ^ swz));
        oacc = __builtin_amdgcn_mfma_f32_16x16x32_bf16(a, wl, oacc, 0, 0, 0);
      }
      #pragma unroll
      for (int r = 0; r < 4; ++r)
        out[(size_t)(16 * b + m4 + r) * T_ * F_ + (size_t)(T_ - 1) * F_ +
            32 * k + 16 * wv + l16] = oacc[r];
    }
  }
}

extern "C" void kernel_launch(void* const* d_in, const int* in_sizes, int n_in,
                              void* d_out, int out_size, void* d_ws, size_t ws_size,
                              hipStream_t stream) {
  const float* z    = (const float*)d_in[0];
  const float* x    = (const float*)d_in[1];
  const float* Wih  = (const float*)d_in[2];
  const float* Whh  = (const float*)d_in[3];
  const float* bih  = (const float*)d_in[4];
  const float* bhh  = (const float*)d_in[5];
  const float* Wlin = (const float*)d_in[6];
  const float* blin = (const float*)d_in[7];
  float* out = (float*)d_out;

  int*   pay    = (int*)d_ws;                              // [0, 128K)
  int*   flags  = (int*)((char*)d_ws + 192 * 1024);        // [192K, +256B)
  int*   pay2   = (int*)((char*)d_ws + 200 * 1024);        // [200K, 328K)
  int*   flags2 = (int*)((char*)d_ws + 328 * 1024);        // [328K, +256B)
  float* dump   = (float*)((char*)d_ws + 332 * 1024);      // [332K, 588K)

  lstm_init<<<64, 256, 0, stream>>>(z, pay, flags, flags2);
  v_nocomm<<<NWG, 256, 0, stream>>>(x, Wih, Whh, bih, bhh, Wlin, blin, dump, pay2);
  v_onlycomm<<<NWG, 256, 0, stream>>>(pay2, flags2);
  v_noA<<<NWG, 256, 0, stream>>>(Whh, bih, bhh, Wlin, blin, dump, pay2, flags2);
  lstm_persist<<<NWG, 256, 0, stream>>>(x, Wih, Whh, bih, bhh, Wlin, blin, out,
                                        pay, flags);
}

// Round 11
// 25714.450 us; speedup vs baseline: 1.6988x; 1.6988x over previous
//
#include <hip/hip_runtime.h>
#include <hip/hip_bf16.h>

#define B_   64
#define T_   2048
#define F_   256
#define H_   512
#define GB   4                    // batch groups (16 rows each)
#define GG   8                    // gate-split WGs per group
#define NWG  (GB*GG)              // 32
#define PAYD 4096                 // packets per group: 16 rows * 256 col-pairs
#define SLOTS 4

typedef __attribute__((ext_vector_type(8))) short bfrag;   // 8 bf16 (MFMA A/B)
typedef __attribute__((ext_vector_type(4))) int   int4v;
typedef __attribute__((ext_vector_type(2))) int   int2v;   // 8B packet {payload, tag}
typedef __attribute__((ext_vector_type(4))) float f32x4;
typedef __attribute__((ext_vector_type(4))) float float4_t;

__device__ __forceinline__ float fsig(float x)  { return 1.0f / (1.0f + __expf(-x)); }
__device__ __forceinline__ float ftanh(float x) { return 2.0f / (1.0f + __expf(-2.0f * x)) - 1.0f; }
__device__ __forceinline__ short f2bf(float f) {
  __hip_bfloat16 h = __float2bfloat16(f);
  return __builtin_bit_cast(short, h);
}

// ---- coherence-point (sc0 sc1: bypass L1+L2, serviced at MALL) ----
__device__ __forceinline__ int2v gload8_cc(const void* p) {
  int2v r;
  asm volatile("global_load_dwordx2 %0, %1, off sc0 sc1" : "=v"(r) : "v"(p));
  return r;
}
__device__ __forceinline__ void gstore8_cc(void* p, int2v d) {
  asm volatile("global_store_dwordx2 %0, %1, off sc0 sc1" :: "v"(p), "v"(d));
}
__device__ __forceinline__ void gstore4_cc(void* p, int d) {
  asm volatile("global_store_dword %0, %1, off sc0 sc1" :: "v"(p), "v"(d));
}
__device__ __forceinline__ int gload_flag(const void* p) {
  int r;
  asm volatile("global_load_dword %0, %1, off sc0 sc1\n\ts_waitcnt vmcnt(0)"
               : "=v"(r) : "v"(p) : "memory");
  return r;
}
__device__ __forceinline__ void vm_drain() {
  asm volatile("s_waitcnt vmcnt(0)" ::: "memory");
  __builtin_amdgcn_sched_barrier(0);   // rule #18
}

// ---------------- init: production slot-0 packets, e_ring region zero, rt flags ----
__global__ void lstm_init(const float* __restrict__ z,
                          unsigned long long* __restrict__ pkt0,
                          unsigned long long* __restrict__ ringpkt,
                          int* __restrict__ rtf) {
  int i = blockIdx.x * blockDim.x + threadIdx.x;     // 0..16383
  if (i < 64) rtf[i] = 0;
  #pragma unroll
  for (int j = 0; j < 4; ++j) ringpkt[i + j * 16384] = 0ull;   // 65536 entries
  int g  = i >> 12;
  int p  = i & 4095;
  int r  = p >> 8;
  int pr = p & 255;
  int row = 16 * g + r;
  unsigned int lo = (unsigned)(unsigned short)f2bf(z[(size_t)row * H_ + 2 * pr])
                  | ((unsigned)(unsigned short)f2bf(z[(size_t)row * H_ + 2 * pr + 1]) << 16);
  pkt0[(size_t)g * PAYD + p] = (unsigned long long)lo;   // tag (hi dword) = 0
}

// ================= MEASUREMENTS (bounded, per-round guards) ==================

// M1: MALL store->load ping-pong, 2048 rounds. dur/2048 = 2x one-way handoff.
__global__ void e_rt(int* e) {
  const int wg = blockIdx.x;
  const int l  = threadIdx.x;
  if (wg == 0) {
    for (int t = 1; t <= 2048; ++t) {
      if (l == 0) gstore4_cc(&e[0], t);
      int g = 0;
      while (gload_flag(&e[16]) < t) { if (++g > 50000) return; }
    }
  } else {
    for (int t = 1; t <= 2048; ++t) {
      int g = 0;
      while (gload_flag(&e[0]) < t) { if (++g > 50000) return; }
      if (l == 0) gstore4_cc(&e[16], t);
    }
  }
}

// M2: production packet protocol, ZERO compute. Poll 16 packets -> store 512/WG.
__global__ void __launch_bounds__(256, 1) e_ring(int2v* __restrict__ pkt) {
  const int wg = blockIdx.x;
  const int b  = wg >> 3;
  const int k  = wg & 7;
  const int tid = threadIdx.x;
  const int wv = tid >> 6;
  const int l16 = (tid & 63) & 15;
  const int qq  = (tid & 63) >> 4;
  const int m4  = qq << 2;
  int guard = 0;
  for (int t = 0; t < T_; ++t) {
    const int2v* pp = pkt + (size_t)((t & 3) * GB + b) * PAYD + tid;
    int2v pv[16];
    while (true) {
      #pragma unroll
      for (int j = 0; j < 16; ++j) pv[j] = gload8_cc(pp + j * 256);
      vm_drain();
      bool ok = true;
      #pragma unroll
      for (int j = 0; j < 16; ++j) ok &= (pv[j].y == t);
      if (__all(ok)) break;
      if (++guard > 40000) return;
      __builtin_amdgcn_s_sleep(2);
    }
    int2v* ps = pkt + (size_t)(((t + 1) & 3) * GB + b) * PAYD;
    #pragma unroll
    for (int r = 0; r < 4; ++r) {
      if ((l16 & 1) == 0) {
        int2v pk; pk.x = pv[r].x; pk.y = t + 1;
        gstore8_cc(ps + (m4 + r) * 256 + (32 * k + 8 * wv + (l16 >> 1)), pk);
      }
    }
  }
}

// M3: LDS+gates-MFMA+activations+out-MFMA compute, ZERO UC traffic.
__global__ void __launch_bounds__(256, 1)
e_comp(const float* __restrict__ Wih, const float* __restrict__ Whh,
       const float* __restrict__ bih, const float* __restrict__ bhh,
       const float* __restrict__ Wlin, const float* __restrict__ blin) {
  __shared__ char smem[49152];
  const int wg  = blockIdx.x;
  const int k   = wg & 7;
  const int tid = threadIdx.x;
  const int wv  = tid >> 6;
  const int l16 = (tid & 63) & 15;
  const int qq  = (tid & 63) >> 4;
  const int swz = (l16 & 7) << 4;

  {
    const int oc = tid >> 3;
    const float* src = Wlin + (size_t)(32 * k + oc) * H_ + (tid & 7) * 64;
    char* dst = smem + 16384 + oc * 1024;
    #pragma unroll
    for (int i = 0; i < 8; ++i) {
      bfrag tmp;
      #pragma unroll
      for (int e = 0; e < 8; ++e) tmp[e] = f2bf(src[i * 8 + e]);
      *(int4v*)(dst + ((((tid & 7) * 128) + i * 16) ^ ((oc & 7) << 4))) =
          __builtin_bit_cast(int4v, tmp);
    }
  }
  bfrag WH[4][16]; float bs[4];
  #pragma unroll
  for (int q = 0; q < 4; ++q) {
    const int grow = q * H_ + k * 64 + wv * 16 + l16;
    #pragma unroll
    for (int kt = 0; kt < 16; ++kt) {
      const float* s = Whh + (size_t)grow * H_ + kt * 32 + qq * 8;
      bfrag w;
      #pragma unroll
      for (int e = 0; e < 8; ++e) w[e] = f2bf(s[e]);
      WH[q][kt] = w;
    }
    bs[q] = bih[grow] + bhh[grow];
  }
  const float blc = (wv < 2) ? blin[32 * k + 16 * wv + l16] : 0.f;
  float c4[4] = {0.f, 0.f, 0.f, 0.f};
  __syncthreads();

  for (int t = 0; t < T_; ++t) {
    int pv[16];
    #pragma unroll
    for (int j = 0; j < 16; ++j) pv[j] = (int)((t * 2654435761u) ^ (j << 8) ^ tid);
    __syncthreads();
    #pragma unroll
    for (int j = 0; j < 16; ++j)
      *(int*)(smem + j * 1024 + ((tid * 4) ^ ((j & 7) << 4))) = pv[j];
    __syncthreads();
    f32x4 acc[4] = {{0,0,0,0},{0,0,0,0},{0,0,0,0},{0,0,0,0}};
    #pragma unroll
    for (int kt = 0; kt < 16; ++kt) {
      bfrag a = *(const bfrag*)(smem + l16 * 1024 + ((kt * 64 + qq * 16) ^ swz));
      #pragma unroll
      for (int q = 0; q < 4; ++q)
        acc[q] = __builtin_amdgcn_mfma_f32_16x16x32_bf16(a, WH[q][kt], acc[q], 0, 0, 0);
    }
    #pragma unroll
    for (int r = 0; r < 4; ++r) {
      float iv = fsig(acc[0][r] + bs[0]);
      float fv = fsig(acc[1][r] + bs[1]);
      float gv = ftanh(acc[2][r] + bs[2]);
      float ov = fsig(acc[3][r] + bs[3]);
      float cn = fv * c4[r] + iv * gv;
      c4[r] = cn;
      float hn = ov * ftanh(cn);
      asm volatile("" :: "v"(hn));            // rule #17: keep live, no DCE
    }
    if (wv < 2) {
      f32x4 oacc = {blc, blc, blc, blc};
      #pragma unroll
      for (int kt = 0; kt < 16; ++kt) {
        bfrag a  = *(const bfrag*)(smem + l16 * 1024 + ((kt * 64 + qq * 16) ^ swz));
        bfrag wl = *(const bfrag*)(smem + 16384 + (16 * wv + l16) * 1024 +
                                   ((kt * 64 + qq * 16) ^ swz));
        oacc = __builtin_amdgcn_mfma_f32_16x16x32_bf16(a, wl, oacc, 0, 0, 0);
      }
      asm volatile("" :: "v"(oacc[0]), "v"(oacc[1]), "v"(oacc[2]), "v"(oacc[3]));
    }
  }
}

// ---------------- persistent LSTM: tag packets, reordered critical path --------
// Changes vs R5/R9: packet reads issued BEFORE phase A (latency merge);
// fire-and-forget tagged stores (no drain/flag in chain); out-GEMM+stores
// moved after packet stores (off the ring cycle). Slot skew <= 2 < 4 (safe).
__global__ void __launch_bounds__(256, 1)
lstm_persist(const float* __restrict__ x,
             const float* __restrict__ Wih,  const float* __restrict__ Whh,
             const float* __restrict__ bih,  const float* __restrict__ bhh,
             const float* __restrict__ Wlin, const float* __restrict__ blin,
             float* __restrict__ out, int2v* __restrict__ pkt)
{
  __shared__ char smem[49152];

  const int wg  = blockIdx.x;
  const int b   = wg >> 3;
  const int k   = wg & 7;
  const int tid = threadIdx.x;
  const int wv  = tid >> 6;
  const int l   = tid & 63;
  const int l16 = l & 15;
  const int qq  = l >> 4;
  const int swz = (l16 & 7) << 4;
  const int m4  = qq << 2;

  {
    const int oc = tid >> 3;
    const float* src = Wlin + (size_t)(32 * k + oc) * H_ + (tid & 7) * 64;
    char* dst = smem + 16384 + oc * 1024;
    #pragma unroll
    for (int i = 0; i < 8; ++i) {
      bfrag tmp;
      #pragma unroll
      for (int e = 0; e < 8; ++e) tmp[e] = f2bf(src[i * 8 + e]);
      *(int4v*)(dst + ((((tid & 7) * 128) + i * 16) ^ ((oc & 7) << 4))) =
          __builtin_bit_cast(int4v, tmp);
    }
  }

  bfrag WH[4][16]; bfrag WI[4][8]; float bs[4];
  #pragma unroll
  for (int q = 0; q < 4; ++q) {
    const int grow = q * H_ + k * 64 + wv * 16 + l16;
    #pragma unroll
    for (int kt = 0; kt < 16; ++kt) {
      const float* s = Whh + (size_t)grow * H_ + kt * 32 + qq * 8;
      bfrag w;
      #pragma unroll
      for (int e = 0; e < 8; ++e) w[e] = f2bf(s[e]);
      WH[q][kt] = w;
    }
    #pragma unroll
    for (int kt = 0; kt < 8; ++kt) {
      const float* s = Wih + (size_t)grow * F_ + kt * 32 + qq * 8;
      bfrag w;
      #pragma unroll
      for (int e = 0; e < 8; ++e) w[e] = f2bf(s[e]);
      WI[q][kt] = w;
    }
    bs[q] = bih[grow] + bhh[grow];
  }
  const float blc = (wv < 2) ? blin[32 * k + 16 * wv + l16] : 0.f;

  float c4[4] = {0.f, 0.f, 0.f, 0.f};
  __syncthreads();

  for (int t = 0; t < T_; ++t) {
    // ---- issue speculative packet reads for h_t (before A: latencies merge) ----
    const int2v* pp = pkt + (size_t)((t & 3) * GB + b) * PAYD + tid;
    int2v pv[16];
    #pragma unroll
    for (int j = 0; j < 16; ++j) pv[j] = gload8_cc(pp + j * 256);

    // ---- A: x-part of gates (packet loads in flight underneath) ----
    f32x4 acc[4] = {{0,0,0,0},{0,0,0,0},{0,0,0,0},{0,0,0,0}};
    {
      const float* xr = x + ((size_t)(16 * b + l16) * T_ + t) * F_ + qq * 8;
      #pragma unroll
      for (int kt = 0; kt < 8; ++kt) {
        float4_t xa = *(const float4_t*)(xr + kt * 32);
        float4_t xb = *(const float4_t*)(xr + kt * 32 + 4);
        bfrag a;
        #pragma unroll
        for (int e = 0; e < 4; ++e) { a[e] = f2bf(xa[e]); a[4 + e] = f2bf(xb[e]); }
        #pragma unroll
        for (int q = 0; q < 4; ++q)
          acc[q] = __builtin_amdgcn_mfma_f32_16x16x32_bf16(a, WI[q][kt], acc[q], 0, 0, 0);
      }
    }

    // ---- validate tags; re-poll on miss ----
    vm_drain();
    {
      bool ok = true;
      #pragma unroll
      for (int j = 0; j < 16; ++j) ok &= (pv[j].y == t);
      while (!__all(ok)) {
        __builtin_amdgcn_s_sleep(2);
        #pragma unroll
        for (int j = 0; j < 16; ++j) pv[j] = gload8_cc(pp + j * 256);
        vm_drain();
        ok = true;
        #pragma unroll
        for (int j = 0; j < 16; ++j) ok &= (pv[j].y == t);
      }
    }
    __syncthreads();    // prior iter's LDS reads (oacc) done

    // ---- stage h-tile to LDS (swizzled) ----
    #pragma unroll
    for (int j = 0; j < 16; ++j)
      *(int*)(smem + j * 1024 + ((tid * 4) ^ ((j & 7) << 4))) = pv[j].x;
    __syncthreads();

    // ---- D: gates h-part only (64 MFMA) ----
    #pragma unroll
    for (int kt = 0; kt < 16; ++kt) {
      bfrag a = *(const bfrag*)(smem + l16 * 1024 + ((kt * 64 + qq * 16) ^ swz));
      #pragma unroll
      for (int q = 0; q < 4; ++q)
        acc[q] = __builtin_amdgcn_mfma_f32_16x16x32_bf16(a, WH[q][kt], acc[q], 0, 0, 0);
    }

    // ---- E: activations + tagged packet stores (fire & forget, ASAP) ----
    int2v* ps = pkt + (size_t)(((t + 1) & 3) * GB + b) * PAYD;
    #pragma unroll
    for (int r = 0; r < 4; ++r) {
      float iv = fsig(acc[0][r] + bs[0]);
      float fv = fsig(acc[1][r] + bs[1]);
      float gv = ftanh(acc[2][r] + bs[2]);
      float ov = fsig(acc[3][r] + bs[3]);
      float cn = fv * c4[r] + iv * gv;
      c4[r] = cn;
      float hn = ov * ftanh(cn);
      int hb = (int)(unsigned short)f2bf(hn);
      int pu = __shfl_xor(hb, 1);
      if ((l16 & 1) == 0) {
        int2v pk;
        pk.x = (hb & 0xffff) | (pu << 16);
        pk.y = t + 1;
        gstore8_cc(ps + (m4 + r) * 256 + (32 * k + 8 * wv + (l16 >> 1)), pk);
      }
    }

    // ---- off-chain: out[t-1] GEMM + store (LDS tile still valid) ----
    if (wv < 2) {
      f32x4 oacc = {blc, blc, blc, blc};
      #pragma unroll
      for (int kt = 0; kt < 16; ++kt) {
        bfrag a  = *(const bfrag*)(smem + l16 * 1024 + ((kt * 64 + qq * 16) ^ swz));
        bfrag wl = *(const bfrag*)(smem + 16384 + (16 * wv + l16) * 1024 +
                                   ((kt * 64 + qq * 16) ^ swz));
        oacc = __builtin_amdgcn_mfma_f32_16x16x32_bf16(a, wl, oacc, 0, 0, 0);
      }
      if (t > 0) {
        #pragma unroll
        for (int r = 0; r < 4; ++r)
          out[(size_t)(16 * b + m4 + r) * T_ * F_ + (size_t)(t - 1) * F_ +
              32 * k + 16 * wv + l16] = oacc[r];
      }
    }
  }

  // ---- tail: out[T-1] from h_T (slot 0, tag T_) ----
  {
    const int2v* pp = pkt + (size_t)((T_ & 3) * GB + b) * PAYD + tid;
    int2v pv[16];
    while (true) {
      #pragma unroll
      for (int j = 0; j < 16; ++j) pv[j] = gload8_cc(pp + j * 256);
      vm_drain();
      bool ok = true;
      #pragma unroll
      for (int j = 0; j < 16; ++j) ok &= (pv[j].y == T_);
      if (__all(ok)) break;
      __builtin_amdgcn_s_sleep(2);
    }
    __syncthreads();
    #pragma unroll
    for (int j = 0; j < 16; ++j)
      *(int*)(smem + j * 1024 + ((tid * 4) ^ ((j & 7) << 4))) = pv[j].x;
    __syncthreads();

    if (wv < 2) {
      f32x4 oacc = {blc, blc, blc, blc};
      #pragma unroll
      for (int kt = 0; kt < 16; ++kt) {
        bfrag a  = *(const bfrag*)(smem + l16 * 1024 + ((kt * 64 + qq * 16) ^ swz));
        bfrag wl = *(const bfrag*)(smem + 16384 + (16 * wv + l16) * 1024 +
                                   ((kt * 64 + qq * 16) ^ swz));
        oacc = __builtin_amdgcn_mfma_f32_16x16x32_bf16(a, wl, oacc, 0, 0, 0);
      }
      #pragma unroll
      for (int r = 0; r < 4; ++r)
        out[(size_t)(16 * b + m4 + r) * T_ * F_ + (size_t)(T_ - 1) * F_ +
            32 * k + 16 * wv + l16] = oacc[r];
    }
  }
}

extern "C" void kernel_launch(void* const* d_in, const int* in_sizes, int n_in,
                              void* d_out, int out_size, void* d_ws, size_t ws_size,
                              hipStream_t stream) {
  const float* z    = (const float*)d_in[0];
  const float* x    = (const float*)d_in[1];
  const float* Wih  = (const float*)d_in[2];
  const float* Whh  = (const float*)d_in[3];
  const float* bih  = (const float*)d_in[4];
  const float* bhh  = (const float*)d_in[5];
  const float* Wlin = (const float*)d_in[6];
  const float* blin = (const float*)d_in[7];
  float* out = (float*)d_out;

  int2v* pkt  = (int2v*)d_ws;                             // [0, 512K) production
  int2v* rpkt = (int2v*)((char*)d_ws + 512 * 1024);       // [512K, 1M) e_ring
  int*   rtf  = (int*)((char*)d_ws + 1024 * 1024);        // [1M, +256B) e_rt

  lstm_init<<<64, 256, 0, stream>>>(z, (unsigned long long*)pkt,
                                    (unsigned long long*)rpkt, rtf);
  e_rt<<<2, 64, 0, stream>>>(rtf);
  e_ring<<<NWG, 256, 0, stream>>>(rpkt);
  e_comp<<<NWG, 256, 0, stream>>>(Wih, Whh, bih, bhh, Wlin, blin);
  lstm_persist<<<NWG, 256, 0, stream>>>(x, Wih, Whh, bih, bhh, Wlin, blin, out, pkt);
}

// Round 12
// 16518.103 us; speedup vs baseline: 2.6447x; 1.5567x over previous
//
#include <hip/hip_runtime.h>
#include <hip/hip_bf16.h>

#define B_   64
#define T_   2048
#define F_   256
#define H_   512
#define GB   4                    // batch groups (16 rows each)
#define GG   8                    // col-split WGs per group (64 h-cols each)
#define NWG  (GB*GG)              // 32
#define PAYD 4096                 // packets per group: 16 rows * 256 col-pairs

typedef __attribute__((ext_vector_type(8))) short bfrag;   // 8 bf16 (MFMA A/B)
typedef __attribute__((ext_vector_type(4))) int   int4v;
typedef __attribute__((ext_vector_type(2))) int   int2v;   // 8B packet {payload, tag}
typedef __attribute__((ext_vector_type(4))) float f32x4;
typedef __attribute__((ext_vector_type(4))) float float4_t;

__device__ __forceinline__ float fsig(float x)  { return 1.0f / (1.0f + __expf(-x)); }
__device__ __forceinline__ float ftanh(float x) { return 2.0f / (1.0f + __expf(-2.0f * x)) - 1.0f; }
__device__ __forceinline__ short f2bf(float f) {
  __hip_bfloat16 h = __float2bfloat16(f);
  return __builtin_bit_cast(short, h);
}

// ---- coherence-point (sc0 sc1: bypass L1+L2, serviced at MALL) ----
__device__ __forceinline__ int2v gload8_cc(const void* p) {
  int2v r;
  asm volatile("global_load_dwordx2 %0, %1, off sc0 sc1" : "=v"(r) : "v"(p));
  return r;
}
__device__ __forceinline__ void gstore8_cc(void* p, int2v d) {
  asm volatile("global_store_dwordx2 %0, %1, off sc0 sc1" :: "v"(p), "v"(d));
}
__device__ __forceinline__ void vm_drain() {
  asm volatile("s_waitcnt vmcnt(0)" ::: "memory");
  __builtin_amdgcn_sched_barrier(0);   // rule #18
}

// ---------------- init: slot-0 packets = h_0 = bf16(z), tag 0 ----------------
__global__ void lstm_init(const float* __restrict__ z,
                          unsigned long long* __restrict__ pkt0) {
  int i = blockIdx.x * blockDim.x + threadIdx.x;     // 0..16383
  int g  = i >> 12;
  int p  = i & 4095;
  int r  = p >> 8;
  int pr = p & 255;
  int row = 16 * g + r;
  unsigned int lo = (unsigned)(unsigned short)f2bf(z[(size_t)row * H_ + 2 * pr])
                  | ((unsigned)(unsigned short)f2bf(z[(size_t)row * H_ + 2 * pr + 1]) << 16);
  pkt0[(size_t)g * PAYD + p] = (unsigned long long)lo;   // tag (hi dword) = 0
}

// ---------------- persistent LSTM, 8 waves / 2-per-SIMD ----------------
// WG(b,k): batch rows [16b,16b+16), h-cols [64k,64k+64), out-cols [32k,32k+32).
// Wave w = (ct = w&3, kh = w>>2): col-tile [64k+16ct, +16), K-half kh.
// Per-wave weights: WH[4][8] (128 VGPR) + WI[4][4] (64) = 192 -> 2 waves/SIMD.
// kh partial gates summed via LDS exchange; kh=1 ct<2 waves do out-GEMM
// (W_lin in LDS) concurrently with kh=0's activations + packet stores.
// Transport: R5's 4-slot tagged packets (fire-and-forget, spec-read under x).
__global__ void __launch_bounds__(512, 1)
lstm_persist(const float* __restrict__ x,
             const float* __restrict__ Wih,  const float* __restrict__ Whh,
             const float* __restrict__ bih,  const float* __restrict__ bhh,
             const float* __restrict__ Wlin, const float* __restrict__ blin,
             float* __restrict__ out, int2v* __restrict__ pkt)
{
  __shared__ char smem[65536];   // [0,16K) h-tile | [16K,48K) W_lin | [48K,64K) xchg

  const int wg  = blockIdx.x;
  const int b   = wg >> 3;
  const int k   = wg & 7;
  const int tid = threadIdx.x;
  const int w   = tid >> 6;
  const int ct  = w & 3;
  const int kh  = w >> 2;
  const int l   = tid & 63;
  const int l16 = l & 15;
  const int qq  = l >> 4;
  const int m4  = qq << 2;
  const int swz = (l16 & 7) << 4;

  // ---- stage W_lin slice (out-cols 32k..32k+32, K=512) to LDS, swizzled ----
  {
    const int oc = tid >> 4;               // 0..31
    const int s  = tid & 15;               // K chunk
    const float* src = Wlin + (size_t)(32 * k + oc) * H_ + s * 32;
    char* dst = smem + 16384 + oc * 1024;
    #pragma unroll
    for (int i = 0; i < 4; ++i) {
      bfrag tmp;
      #pragma unroll
      for (int e = 0; e < 8; ++e) tmp[e] = f2bf(src[i * 8 + e]);
      *(int4v*)(dst + ((s * 64 + i * 16) ^ ((oc & 7) << 4))) =
          __builtin_bit_cast(int4v, tmp);
    }
  }

  // ---- persistent weight fragments (K-half kh only) ----
  bfrag WH[4][8]; bfrag WI[4][4]; float bs[4];
  #pragma unroll
  for (int q = 0; q < 4; ++q) {
    const int grow = q * H_ + k * 64 + ct * 16 + l16;
    #pragma unroll
    for (int kt2 = 0; kt2 < 8; ++kt2) {
      const float* s = Whh + (size_t)grow * H_ + (8 * kh + kt2) * 32 + qq * 8;
      bfrag wv_;
      #pragma unroll
      for (int e = 0; e < 8; ++e) wv_[e] = f2bf(s[e]);
      WH[q][kt2] = wv_;
    }
    #pragma unroll
    for (int kt2 = 0; kt2 < 4; ++kt2) {
      const float* s = Wih + (size_t)grow * F_ + (4 * kh + kt2) * 32 + qq * 8;
      bfrag wv_;
      #pragma unroll
      for (int e = 0; e < 8; ++e) wv_[e] = f2bf(s[e]);
      WI[q][kt2] = wv_;
    }
    bs[q] = bih[grow] + bhh[grow];
  }
  const float blc = (kh == 1 && ct < 2) ? blin[32 * k + 16 * ct + l16] : 0.f;

  float c4[4] = {0.f, 0.f, 0.f, 0.f};     // cell state (kh==0 waves)
  __syncthreads();

  for (int t = 0; t < T_; ++t) {
    // ---- speculative packet reads (8/thread), in flight under x-part ----
    const int2v* pp = pkt + (size_t)((t & 3) * GB + b) * PAYD + tid;
    int2v pv[8];
    #pragma unroll
    for (int j = 0; j < 8; ++j) pv[j] = gload8_cc(pp + j * 512);

    // ---- x-part of gates (this wave's K-quarter of x) ----
    f32x4 acc[4] = {{0,0,0,0},{0,0,0,0},{0,0,0,0},{0,0,0,0}};
    {
      const float* xr = x + ((size_t)(16 * b + l16) * T_ + t) * F_ + qq * 8;
      #pragma unroll
      for (int kt2 = 0; kt2 < 4; ++kt2) {
        const int kt = 4 * kh + kt2;
        float4_t xa = *(const float4_t*)(xr + kt * 32);
        float4_t xb = *(const float4_t*)(xr + kt * 32 + 4);
        bfrag a;
        #pragma unroll
        for (int e = 0; e < 4; ++e) { a[e] = f2bf(xa[e]); a[4 + e] = f2bf(xb[e]); }
        #pragma unroll
        for (int q = 0; q < 4; ++q)
          acc[q] = __builtin_amdgcn_mfma_f32_16x16x32_bf16(a, WI[q][kt2], acc[q], 0, 0, 0);
      }
    }

    // ---- validate tags; re-poll on miss ----
    vm_drain();
    {
      bool ok = true;
      #pragma unroll
      for (int j = 0; j < 8; ++j) ok &= (pv[j].y == t);
      while (!__all(ok)) {
        __builtin_amdgcn_s_sleep(2);
        #pragma unroll
        for (int j = 0; j < 8; ++j) pv[j] = gload8_cc(pp + j * 512);
        vm_drain();
        ok = true;
        #pragma unroll
        for (int j = 0; j < 8; ++j) ok &= (pv[j].y == t);
      }
    }
    __syncthreads();                  // prior-iter h-tile/xchg readers done

    // ---- stage h-tile [16][512]bf16 to LDS (swizzled) ----
    #pragma unroll
    for (int j = 0; j < 8; ++j) {
      const int P = tid + j * 512;
      *(int*)(smem + (P >> 8) * 1024 + (((P & 255) * 4) ^ (((P >> 8) & 7) << 4))) = pv[j].x;
    }
    __syncthreads();

    // ---- gates h-part (this wave's K-half): 32 MFMA ----
    #pragma unroll
    for (int kt2 = 0; kt2 < 8; ++kt2) {
      const int kt = 8 * kh + kt2;
      bfrag a = *(const bfrag*)(smem + l16 * 1024 + ((kt * 64 + qq * 16) ^ swz));
      #pragma unroll
      for (int q = 0; q < 4; ++q)
        acc[q] = __builtin_amdgcn_mfma_f32_16x16x32_bf16(a, WH[q][kt2], acc[q], 0, 0, 0);
    }

    // ---- partial exchange: kh=1 writes, kh=0 sums ----
    if (kh == 1) {
      #pragma unroll
      for (int q = 0; q < 4; ++q)
        *(f32x4*)(smem + 49152 + ct * 4096 + q * 1024 + l * 16) = acc[q];
    }
    __syncthreads();

    if (kh == 0) {
      #pragma unroll
      for (int q = 0; q < 4; ++q)
        acc[q] += *(const f32x4*)(smem + 49152 + ct * 4096 + q * 1024 + l * 16);

      // ---- activations, state, tagged packet stores (fire & forget) ----
      int2v* ps = pkt + (size_t)(((t + 1) & 3) * GB + b) * PAYD;
      #pragma unroll
      for (int r = 0; r < 4; ++r) {
        float iv = fsig(acc[0][r] + bs[0]);
        float fv = fsig(acc[1][r] + bs[1]);
        float gv = ftanh(acc[2][r] + bs[2]);
        float ov = fsig(acc[3][r] + bs[3]);
        float cn = fv * c4[r] + iv * gv;
        c4[r] = cn;
        float hn = ov * ftanh(cn);
        int hb = (int)(unsigned short)f2bf(hn);
        int pu = __shfl_xor(hb, 1);
        if ((l16 & 1) == 0) {
          int2v pk;
          pk.x = (hb & 0xffff) | (pu << 16);
          pk.y = t + 1;
          gstore8_cc(ps + (m4 + r) * 256 + (32 * k + 8 * ct + (l16 >> 1)), pk);
        }
      }
    } else if (ct < 2) {
      // ---- out[t-1] GEMM (16 cols, full K) from LDS, concurrent with kh=0 ----
      f32x4 oacc = {blc, blc, blc, blc};
      const int oc = 16 * ct + l16;
      #pragma unroll
      for (int kt = 0; kt < 16; ++kt) {
        bfrag a  = *(const bfrag*)(smem + l16 * 1024 + ((kt * 64 + qq * 16) ^ swz));
        bfrag wl = *(const bfrag*)(smem + 16384 + oc * 1024 +
                                   ((kt * 64 + qq * 16) ^ ((oc & 7) << 4)));
        oacc = __builtin_amdgcn_mfma_f32_16x16x32_bf16(a, wl, oacc, 0, 0, 0);
      }
      if (t > 0) {
        #pragma unroll
        for (int r = 0; r < 4; ++r)
          out[(size_t)(16 * b + m4 + r) * T_ * F_ + (size_t)(t - 1) * F_ +
              32 * k + 16 * ct + l16] = oacc[r];
      }
    }
  }

  // ---- tail: out[T-1] from h_T (slot T_&3 == 0, tag T_) ----
  {
    const int2v* pp = pkt + (size_t)((T_ & 3) * GB + b) * PAYD + tid;
    int2v pv[8];
    while (true) {
      #pragma unroll
      for (int j = 0; j < 8; ++j) pv[j] = gload8_cc(pp + j * 512);
      vm_drain();
      bool ok = true;
      #pragma unroll
      for (int j = 0; j < 8; ++j) ok &= (pv[j].y == T_);
      if (__all(ok)) break;
      __builtin_amdgcn_s_sleep(2);
    }
    __syncthreads();
    #pragma unroll
    for (int j = 0; j < 8; ++j) {
      const int P = tid + j * 512;
      *(int*)(smem + (P >> 8) * 1024 + (((P & 255) * 4) ^ (((P >> 8) & 7) << 4))) = pv[j].x;
    }
    __syncthreads();

    if (kh == 1 && ct < 2) {
      f32x4 oacc = {blc, blc, blc, blc};
      const int oc = 16 * ct + l16;
      #pragma unroll
      for (int kt = 0; kt < 16; ++kt) {
        bfrag a  = *(const bfrag*)(smem + l16 * 1024 + ((kt * 64 + qq * 16) ^ swz));
        bfrag wl = *(const bfrag*)(smem + 16384 + oc * 1024 +
                                   ((kt * 64 + qq * 16) ^ ((oc & 7) << 4)));
        oacc = __builtin_amdgcn_mfma_f32_16x16x32_bf16(a, wl, oacc, 0, 0, 0);
      }
      #pragma unroll
      for (int r = 0; r < 4; ++r)
        out[(size_t)(16 * b + m4 + r) * T_ * F_ + (size_t)(T_ - 1) * F_ +
            32 * k + 16 * ct + l16] = oacc[r];
    }
  }
}

extern "C" void kernel_launch(void* const* d_in, const int* in_sizes, int n_in,
                              void* d_out, int out_size, void* d_ws, size_t ws_size,
                              hipStream_t stream) {
  const float* z    = (const float*)d_in[0];
  const float* x    = (const float*)d_in[1];
  const float* Wih  = (const float*)d_in[2];
  const float* Whh  = (const float*)d_in[3];
  const float* bih  = (const float*)d_in[4];
  const float* bhh  = (const float*)d_in[5];
  const float* Wlin = (const float*)d_in[6];
  const float* blin = (const float*)d_in[7];
  float* out = (float*)d_out;

  int2v* pkt = (int2v*)d_ws;   // 4 slots * 4 groups * 4096 pkts * 8B = 512 KB

  lstm_init<<<64, 256, 0, stream>>>(z, (unsigned long long*)pkt);
  lstm_persist<<<NWG, 512, 0, stream>>>(x, Wih, Whh, bih, bhh, Wlin, blin, out, pkt);
}